// Round 5
// baseline (822.367 us; speedup 1.0000x reference)
//
#include <hip/hip_runtime.h>
#include <math.h>

// DGCN v3: dense-MFMA everything.
//   A2 = A@A (fp32->bf16); S1 = A@X, S2 = A2@X as two independent bf16 GEMMs (K=512).
//   Mi[n] = (dcw @ W_ih[n]^T)^T via MFMA (no LDS).
//   GRU: frag-packed LDS layout -> every B-frag read is base + lane*16 (conflict-free,
//   near-zero address VALU); packed ushort4 h writes; 1 barrier/step; T14 s-prefetch.

#define B_ 64
#define N_ 512
#define W_ 24
#define F_ 16
#define H_ 128
#define G3 384
#define XCOLS 24576   // B*W*F  (j = b*384 + t*16 + f)

typedef __attribute__((ext_vector_type(8))) short short8;
typedef __attribute__((ext_vector_type(4))) float f32x4;
#define MFMA __builtin_amdgcn_mfma_f32_16x16x32_bf16

__device__ __forceinline__ unsigned short f2bf(float f) {
  unsigned int u = __float_as_uint(f);
  u += 0x7FFFu + ((u >> 16) & 1u);
  return (unsigned short)(u >> 16);
}
__device__ __forceinline__ float bf2f(unsigned short s) {
  return __uint_as_float(((unsigned int)s) << 16);
}

// ---------------- x -> bf16 ----------------
__global__ __launch_bounds__(256) void cvt_bf16(const float* __restrict__ src,
                                                unsigned short* __restrict__ dst) {
  size_t i = ((size_t)blockIdx.x * 256 + threadIdx.x) * 8;
  const float4* p = (const float4*)(src + i);
  float4 a = p[0], b = p[1];
  short8 o;
  o[0]=(short)f2bf(a.x); o[1]=(short)f2bf(a.y); o[2]=(short)f2bf(a.z); o[3]=(short)f2bf(a.w);
  o[4]=(short)f2bf(b.x); o[5]=(short)f2bf(b.y); o[6]=(short)f2bf(b.z); o[7]=(short)f2bf(b.w);
  *(short8*)(dst + i) = o;
}

// ---------------- abf = bf16(A); a2bf = bf16(A@A) ----------------
__global__ __launch_bounds__(256) void ab_build(const float* __restrict__ A,
                                                unsigned short* __restrict__ asbf) {
  __shared__ float arow[4 * N_];
  const int blk = blockIdx.x;      // 128 blocks x 4 rows
  const int tid = threadIdx.x;
  for (int i = tid; i < 4 * N_; i += 256) {
    float v = A[(size_t)blk * 2048 + i];
    arow[i] = v;
    asbf[(size_t)blk * 2048 + i] = f2bf(v);
  }
  __syncthreads();
  float acc[4][2] = {};
  for (int k = 0; k < N_; ++k) {
    float a0 = A[(size_t)k * N_ + tid];
    float a1 = A[(size_t)k * N_ + 256 + tid];
    #pragma unroll
    for (int r = 0; r < 4; ++r) {
      float ar = arow[r * N_ + k];
      acc[r][0] += ar * a0;
      acc[r][1] += ar * a1;
    }
  }
  #pragma unroll
  for (int r = 0; r < 4; ++r) {
    asbf[(size_t)N_ * N_ + (blk * 4 + r) * N_ + tid]       = f2bf(acc[r][0]);
    asbf[(size_t)N_ * N_ + (blk * 4 + r) * N_ + 256 + tid] = f2bf(acc[r][1]);
  }
}

// ---------------- combined dc weights (bf16): dcwbf[48][128] ----------------
__global__ __launch_bounds__(256) void dcwbf_build(const float* __restrict__ dc,
                                                   unsigned short* __restrict__ dcwbf) {
  for (int i = threadIdx.x; i < 48 * H_; i += 256) {
    int f = i >> 7, j = i & 127;
    float v;
    if (f < 16)      v = dc[f * H_ + j];
    else if (f < 32) v = dc[f * H_ + j] + dc[(f + 16) * H_ + j];
    else             v = dc[(f + 16) * H_ + j] + dc[(f + 32) * H_ + j];
    dcwbf[i] = f2bf(v);
  }
}

// ---------------- Mi[n][g][64] = (dcw @ W_ih[n]^T)^T via MFMA ----------------
__global__ __launch_bounds__(512) void prep_mi(const float* __restrict__ W_ih,
                                               const unsigned short* __restrict__ dcwbf,
                                               unsigned short* __restrict__ Mi) {
  const int n = blockIdx.x, tid = threadIdx.x;
  const int w = tid >> 6, l = tid & 63, l15 = l & 15, lhi = l >> 4;
  unsigned short* mi_n = Mi + (size_t)n * G3 * 64;
  // zero-fill pad cols 48..63
  for (int i = tid; i < G3 * 16; i += 512)
    mi_n[(i >> 4) * 64 + 48 + (i & 15)] = 0;

  // B-frags: dcw rows f (3 f-tiles), contiguous k
  short8 bft[3][4];
  #pragma unroll
  for (int ft = 0; ft < 3; ++ft)
    #pragma unroll
    for (int ks = 0; ks < 4; ++ks)
      bft[ft][ks] = *(const short8*)(dcwbf + (ft * 16 + l15) * H_ + ks * 32 + lhi * 8);

  // A-frags: W_ih rows g (3 g-tiles per wave), fp32 -> bf16
  f32x4 acc[3][3];
  #pragma unroll
  for (int gt = 0; gt < 3; ++gt)
    #pragma unroll
    for (int ft = 0; ft < 3; ++ft)
      acc[gt][ft] = (f32x4){0.f, 0.f, 0.f, 0.f};

  #pragma unroll
  for (int gt = 0; gt < 3; ++gt) {
    const int g = (w * 3 + gt) * 16 + l15;
    const float* wr = W_ih + ((size_t)n * G3 + g) * H_;
    #pragma unroll
    for (int ks = 0; ks < 4; ++ks) {
      const float4* p = (const float4*)(wr + ks * 32 + lhi * 8);
      float4 a = p[0], b = p[1];
      short8 af;
      af[0]=(short)f2bf(a.x); af[1]=(short)f2bf(a.y); af[2]=(short)f2bf(a.z); af[3]=(short)f2bf(a.w);
      af[4]=(short)f2bf(b.x); af[5]=(short)f2bf(b.y); af[6]=(short)f2bf(b.z); af[7]=(short)f2bf(b.w);
      #pragma unroll
      for (int ft = 0; ft < 3; ++ft)
        acc[gt][ft] = MFMA(af, bft[ft][ks], acc[gt][ft], 0, 0, 0);
    }
  }
  #pragma unroll
  for (int gt = 0; gt < 3; ++gt) {
    const int g0 = (w * 3 + gt) * 16;
    #pragma unroll
    for (int ft = 0; ft < 3; ++ft)
      #pragma unroll
      for (int r = 0; r < 4; ++r)
        mi_n[(size_t)(g0 + lhi * 4 + r) * 64 + ft * 16 + l15] = f2bf(acc[gt][ft][r]);
  }
}

// ---------------- S1 = A@X, S2 = A2@X  (z selects hop), K=512 ----------------
__global__ __launch_bounds__(512) void gemm_s(const unsigned short* __restrict__ xbf,
                                              const unsigned short* __restrict__ asbf,
                                              unsigned short* __restrict__ S1,
                                              unsigned short* __restrict__ S2) {
  __shared__ unsigned short Al[128 * 72];
  __shared__ unsigned short Xl[256 * 72];
  const int z = blockIdx.z;
  const int m0 = blockIdx.y * 128;
  const int j0 = blockIdx.x * 256;
  const unsigned short* As = asbf + (size_t)z * N_ * N_;
  unsigned short* Sd = z ? S2 : S1;
  const int tid = threadIdx.x;
  const int w = tid >> 6, l = tid & 63, l15 = l & 15, lhi = l >> 4;
  const int wm = w >> 2, wj = w & 3;

  f32x4 acc[4][4];
  #pragma unroll
  for (int mt = 0; mt < 4; ++mt)
    #pragma unroll
    for (int jt = 0; jt < 4; ++jt)
      acc[mt][jt] = (f32x4){0.f, 0.f, 0.f, 0.f};

  for (int kt = 0; kt < 8; ++kt) {
    const int k0 = kt * 64;
    // stage A-tile [128 rows n][64 k=m], pad 72
    #pragma unroll
    for (int it = 0; it < 2; ++it) {
      int idx = it * 512 + tid;
      int row = idx >> 3, mc = (idx & 7) * 8;
      short8 v = *(const short8*)(As + (size_t)(m0 + row) * N_ + k0 + mc);
      *(short8*)&Al[row * 72 + mc] = v;
    }
    // stage X-tile transposed: Xl[j 256][k 64], pad 72
    #pragma unroll
    for (int it = 0; it < 4; ++it) {
      int idx = it * 512 + tid;
      int k = idx & 63, jc = idx >> 6;           // jc 0..31
      int j = j0 + jc * 8;
      int b = j / 384, wf = j - b * 384;
      short8 v = *(const short8*)(xbf + ((size_t)(b * N_ + k0 + k)) * 384 + wf);
      #pragma unroll
      for (int i = 0; i < 8; ++i)
        Xl[(jc * 8 + i) * 72 + k] = (unsigned short)v[i];
    }
    __syncthreads();
    #pragma unroll
    for (int ks = 0; ks < 2; ++ks) {
      short8 af[4], bf[4];
      #pragma unroll
      for (int mt = 0; mt < 4; ++mt)
        af[mt] = *(const short8*)&Al[(wm * 64 + mt * 16 + l15) * 72 + ks * 32 + lhi * 8];
      #pragma unroll
      for (int jt = 0; jt < 4; ++jt)
        bf[jt] = *(const short8*)&Xl[(wj * 64 + jt * 16 + l15) * 72 + ks * 32 + lhi * 8];
      #pragma unroll
      for (int mt = 0; mt < 4; ++mt)
        #pragma unroll
        for (int jt = 0; jt < 4; ++jt)
          acc[mt][jt] = MFMA(af[mt], bf[jt], acc[mt][jt], 0, 0, 0);
    }
    __syncthreads();
  }
  #pragma unroll
  for (int mt = 0; mt < 4; ++mt)
    #pragma unroll
    for (int jt = 0; jt < 4; ++jt)
      #pragma unroll
      for (int r = 0; r < 4; ++r) {
        int row = m0 + wm * 64 + mt * 16 + lhi * 4 + r;
        int col = j0 + wj * 64 + jt * 16 + l15;
        Sd[(size_t)row * XCOLS + col] = f2bf(acc[mt][jt][r]);
      }
}

// ---------------- fused GRU v3: frag-packed LDS ----------------
// s frag: s_lds[buf][mt][ks2][lane][8]  (feature k = ks2*32 + (lane>>4)*8 + j, batch = mt*16 + (lane&15))
// h frag: h_lds[buf][mt][ks4][lane][8]  (hidden  k = ks4*32 + (lane>>4)*8 + j)
__global__ __launch_bounds__(512, 4) void gru_mfma(
    const unsigned short* __restrict__ xbf, const unsigned short* __restrict__ S1,
    const unsigned short* __restrict__ S2, const unsigned short* __restrict__ Mi,
    const float* __restrict__ W_hh, const float* __restrict__ b_ih,
    const float* __restrict__ b_hh, const float* __restrict__ W_out,
    const float* __restrict__ b_out, float* __restrict__ out) {
  __shared__ __align__(16) unsigned short s_lds[2 * 4096];   // 2 buf * 4 mt * 2 ks * 512
  __shared__ __align__(16) unsigned short h_lds[2 * 8192];   // 2 buf * 4 mt * 4 ks * 512
  __shared__ float wout_lds[H_ * F_];

  const int n = blockIdx.x;
  const int tid = threadIdx.x;
  const int w = tid >> 6;        // wave = hidden tile
  const int l = tid & 63;
  const int l15 = l & 15;
  const int lhi = l >> 4;

  { // zero h buf0
    uint* hz = (uint*)h_lds;
    for (int i = tid; i < 4096; i += 512) hz[i] = 0u;
  }
  for (int i = tid; i < H_ * F_; i += 512) wout_lds[i] = W_out[i];

  // weight fragments (register-resident, all 24 steps)
  short8 whf[3][4];
  short8 mif[3][2];
  const float* whh_n = W_hh + (size_t)n * G3 * H_;
  const unsigned short* mi_n = Mi + (size_t)n * G3 * 64;
  #pragma unroll
  for (int g3 = 0; g3 < 3; ++g3) {
    const int grow = g3 * H_ + w * 16 + l15;
    #pragma unroll
    for (int ks = 0; ks < 4; ++ks) {
      const float4* p = (const float4*)(whh_n + (size_t)grow * H_ + ks * 32 + lhi * 8);
      float4 a = p[0], b2 = p[1];
      short8 r;
      r[0]=(short)f2bf(a.x); r[1]=(short)f2bf(a.y); r[2]=(short)f2bf(a.z); r[3]=(short)f2bf(a.w);
      r[4]=(short)f2bf(b2.x); r[5]=(short)f2bf(b2.y); r[6]=(short)f2bf(b2.z); r[7]=(short)f2bf(b2.w);
      whf[g3][ks] = r;
    }
    #pragma unroll
    for (int ks = 0; ks < 2; ++ks)
      mif[g3][ks] = *(const short8*)(mi_n + (size_t)grow * 64 + ks * 32 + lhi * 8);
  }
  // biases in C registers
  f32x4 cR, cZ, cN, cHN, zero4 = {0.f, 0.f, 0.f, 0.f};
  {
    const float* bi = b_ih + n * G3;
    const float* bh = b_hh + n * G3;
    #pragma unroll
    for (int r = 0; r < 4; ++r) {
      int g0 = w * 16 + lhi * 4 + r;
      cR[r]  = bi[g0] + bh[g0];
      cZ[r]  = bi[H_ + g0] + bh[H_ + g0];
      cN[r]  = bi[2 * H_ + g0];
      cHN[r] = bh[2 * H_ + g0];
    }
  }

  // staging geometry (one 16B chunk per thread per step)
  const int smt = tid >> 7, sks = (tid >> 6) & 1, slane = tid & 63;
  const int sc = slane & 15, sfb = sks * 4 + (slane >> 4);
  const int sb = smt * 16 + sc;
  const bool szero = (sfb >= 6);
  const unsigned short* ssrc;
  if (sfb < 2)      ssrc = xbf + ((size_t)(sb * N_ + n)) * 384 + (sfb & 1) * 8;
  else if (sfb < 4) ssrc = S1 + (size_t)n * XCOLS + sb * 384 + (sfb & 1) * 8;
  else              ssrc = S2 + (size_t)n * XCOLS + sb * 384 + (sfb & 1) * 8;

  // prologue: s(t=0) into buf0; zero-chunks into BOTH buffers
  {
    short8 sv = {0,0,0,0,0,0,0,0};
    if (!szero) sv = *(const short8*)ssrc;
    *(short8*)&s_lds[tid * 8] = sv;
    if (szero) *(short8*)&s_lds[4096 + tid * 8] = sv;
  }
  __syncthreads();

  // combine write geometry
  const int hks = w >> 1;
  const int lanep = ((w & 1) * 2 + (lhi >> 1)) * 16 + l15;
  const int j0p = (lhi & 1) * 4;

  int cur = 0;
  for (int t = 0; t < W_; ++t) {
    const int nxt = cur ^ 1;
    const bool dn = (t + 1 < W_);
    short8 svn;
    if (dn && !szero) svn = *(const short8*)(ssrc + (size_t)(t + 1) * 16);

    #pragma unroll
    for (int mt = 0; mt < 4; ++mt) {
      const unsigned short* sb_ = &s_lds[cur * 4096 + mt * 1024 + l * 8];
      const unsigned short* hb_ = &h_lds[cur * 8192 + mt * 2048 + l * 8];
      short8 bs0 = *(const short8*)sb_;
      short8 bs1 = *(const short8*)(sb_ + 512);
      short8 bh0 = *(const short8*)hb_;
      short8 bh1 = *(const short8*)(hb_ + 512);
      short8 bh2 = *(const short8*)(hb_ + 1024);
      short8 bh3 = *(const short8*)(hb_ + 1536);

      f32x4 aR = MFMA(mif[0][0], bs0, cR, 0, 0, 0);
      f32x4 aZ = MFMA(mif[1][0], bs0, cZ, 0, 0, 0);
      f32x4 aN = MFMA(mif[2][0], bs0, cN, 0, 0, 0);
      aR = MFMA(mif[0][1], bs1, aR, 0, 0, 0);
      aZ = MFMA(mif[1][1], bs1, aZ, 0, 0, 0);
      aN = MFMA(mif[2][1], bs1, aN, 0, 0, 0);
      f32x4 hR = MFMA(whf[0][0], bh0, zero4, 0, 0, 0);
      f32x4 hZ = MFMA(whf[1][0], bh0, zero4, 0, 0, 0);
      f32x4 hN = MFMA(whf[2][0], bh0, cHN, 0, 0, 0);
      hR = MFMA(whf[0][1], bh1, hR, 0, 0, 0);
      hZ = MFMA(whf[1][1], bh1, hZ, 0, 0, 0);
      hN = MFMA(whf[2][1], bh1, hN, 0, 0, 0);
      hR = MFMA(whf[0][2], bh2, hR, 0, 0, 0);
      hZ = MFMA(whf[1][2], bh2, hZ, 0, 0, 0);
      hN = MFMA(whf[2][2], bh2, hN, 0, 0, 0);
      hR = MFMA(whf[0][3], bh3, hR, 0, 0, 0);
      hZ = MFMA(whf[1][3], bh3, hZ, 0, 0, 0);
      hN = MFMA(whf[2][3], bh3, hN, 0, 0, 0);

      const int hidx = cur * 8192 + mt * 2048 + hks * 512 + lanep * 8 + j0p;
      const int nidx = nxt * 8192 + mt * 2048 + hks * 512 + lanep * 8 + j0p;
      ushort4 hp4 = *(const ushort4*)&h_lds[hidx];
      ushort4 hn4;
      #pragma unroll
      for (int r = 0; r < 4; ++r) {
        float rg = __builtin_amdgcn_rcpf(1.f + __expf(-(aR[r] + hR[r])));
        float zg = __builtin_amdgcn_rcpf(1.f + __expf(-(aZ[r] + hZ[r])));
        float tt = aN[r] + rg * hN[r];
        float e  = __expf(2.f * tt);
        float th = 1.f - 2.f * __builtin_amdgcn_rcpf(e + 1.f);
        float hp = bf2f(r == 0 ? hp4.x : r == 1 ? hp4.y : r == 2 ? hp4.z : hp4.w);
        float hv = th + zg * (hp - th);
        unsigned short hb = f2bf(hv);
        if (r == 0) hn4.x = hb; else if (r == 1) hn4.y = hb;
        else if (r == 2) hn4.z = hb; else hn4.w = hb;
      }
      *(ushort4*)&h_lds[nidx] = hn4;
    }

    if (dn && !szero) *(short8*)&s_lds[nxt * 4096 + tid * 8] = svn;
    __syncthreads();
    cur = nxt;
  }

  // epilogue: out[b][n][f] = h . W_out[:,f] + b_out[f]
  for (int e = tid; e < B_ * F_; e += 512) {
    const int b = e >> 4, f = e & 15;
    const int mt = b >> 4, c = b & 15;
    float acc = b_out[f];
    #pragma unroll
    for (int ks = 0; ks < 4; ++ks)
      #pragma unroll
      for (int lh = 0; lh < 4; ++lh) {
        const unsigned short* hb = &h_lds[cur * 8192 + mt * 2048 + ks * 512 + (lh * 16 + c) * 8];
        #pragma unroll
        for (int jj = 0; jj < 8; ++jj)
          acc += bf2f(hb[jj]) * wout_lds[(ks * 32 + lh * 8 + jj) * F_ + f];
      }
    out[((size_t)b * N_ + n) * F_ + f] = acc;
  }
}

extern "C" void kernel_launch(void* const* d_in, const int* in_sizes, int n_in,
                              void* d_out, int out_size, void* d_ws, size_t ws_size,
                              hipStream_t stream) {
  const float* x     = (const float*)d_in[0];
  const float* A_fw  = (const float*)d_in[1];
  const float* dc    = (const float*)d_in[2];
  const float* W_ih  = (const float*)d_in[3];
  const float* W_hh  = (const float*)d_in[4];
  const float* b_ih  = (const float*)d_in[5];
  const float* b_hh  = (const float*)d_in[6];
  const float* W_out = (const float*)d_in[7];
  const float* b_out = (const float*)d_in[8];
  float* out = (float*)d_out;

  // workspace (~102 MB)
  unsigned short* xbf   = (unsigned short*)d_ws;            // 12.58M
  unsigned short* S1    = xbf + (size_t)B_ * N_ * W_ * F_;  // 12.58M
  unsigned short* S2    = S1 + (size_t)N_ * XCOLS;          // 12.58M
  unsigned short* Mi    = S2 + (size_t)N_ * XCOLS;          // 12.58M
  unsigned short* asbf  = Mi + (size_t)N_ * G3 * 64;        // 2*512*512
  unsigned short* dcwbf = asbf + 2 * N_ * N_;               // 48*128

  cvt_bf16<<<dim3(6144), dim3(256), 0, stream>>>(x, xbf);
  ab_build<<<dim3(128), dim3(256), 0, stream>>>(A_fw, asbf);
  dcwbf_build<<<dim3(1), dim3(256), 0, stream>>>(dc, dcwbf);
  prep_mi<<<dim3(N_), dim3(512), 0, stream>>>(W_ih, dcwbf, Mi);
  gemm_s<<<dim3(96, 4, 2), dim3(512), 0, stream>>>(xbf, asbf, S1, S2);
  gru_mfma<<<dim3(N_), dim3(512), 0, stream>>>(xbf, S1, S2, Mi, W_hh, b_ih, b_hh,
                                               W_out, b_out, out);
}

// Round 6
// 522.982 us; speedup vs baseline: 1.5725x; 1.5725x over previous
//
#include <hip/hip_runtime.h>
#include <math.h>

// DGCN v3.1: identical to v3 except gru_mfma uses plain __launch_bounds__(512).
// v3's (512,4) capped VGPR at 64 -> compiler rematerialized the 72-VGPR weight
// fragments from global every step (FETCH 100MB -> 1.45GB, 278 -> 486us).

#define B_ 64
#define N_ 512
#define W_ 24
#define F_ 16
#define H_ 128
#define G3 384
#define XCOLS 24576   // B*W*F  (j = b*384 + t*16 + f)

typedef __attribute__((ext_vector_type(8))) short short8;
typedef __attribute__((ext_vector_type(4))) float f32x4;
#define MFMA __builtin_amdgcn_mfma_f32_16x16x32_bf16

__device__ __forceinline__ unsigned short f2bf(float f) {
  unsigned int u = __float_as_uint(f);
  u += 0x7FFFu + ((u >> 16) & 1u);
  return (unsigned short)(u >> 16);
}
__device__ __forceinline__ float bf2f(unsigned short s) {
  return __uint_as_float(((unsigned int)s) << 16);
}

// ---------------- x -> bf16 ----------------
__global__ __launch_bounds__(256) void cvt_bf16(const float* __restrict__ src,
                                                unsigned short* __restrict__ dst) {
  size_t i = ((size_t)blockIdx.x * 256 + threadIdx.x) * 8;
  const float4* p = (const float4*)(src + i);
  float4 a = p[0], b = p[1];
  short8 o;
  o[0]=(short)f2bf(a.x); o[1]=(short)f2bf(a.y); o[2]=(short)f2bf(a.z); o[3]=(short)f2bf(a.w);
  o[4]=(short)f2bf(b.x); o[5]=(short)f2bf(b.y); o[6]=(short)f2bf(b.z); o[7]=(short)f2bf(b.w);
  *(short8*)(dst + i) = o;
}

// ---------------- abf = bf16(A); a2bf = bf16(A@A) ----------------
__global__ __launch_bounds__(256) void ab_build(const float* __restrict__ A,
                                                unsigned short* __restrict__ asbf) {
  __shared__ float arow[4 * N_];
  const int blk = blockIdx.x;      // 128 blocks x 4 rows
  const int tid = threadIdx.x;
  for (int i = tid; i < 4 * N_; i += 256) {
    float v = A[(size_t)blk * 2048 + i];
    arow[i] = v;
    asbf[(size_t)blk * 2048 + i] = f2bf(v);
  }
  __syncthreads();
  float acc[4][2] = {};
  for (int k = 0; k < N_; ++k) {
    float a0 = A[(size_t)k * N_ + tid];
    float a1 = A[(size_t)k * N_ + 256 + tid];
    #pragma unroll
    for (int r = 0; r < 4; ++r) {
      float ar = arow[r * N_ + k];
      acc[r][0] += ar * a0;
      acc[r][1] += ar * a1;
    }
  }
  #pragma unroll
  for (int r = 0; r < 4; ++r) {
    asbf[(size_t)N_ * N_ + (blk * 4 + r) * N_ + tid]       = f2bf(acc[r][0]);
    asbf[(size_t)N_ * N_ + (blk * 4 + r) * N_ + 256 + tid] = f2bf(acc[r][1]);
  }
}

// ---------------- combined dc weights (bf16): dcwbf[48][128] ----------------
__global__ __launch_bounds__(256) void dcwbf_build(const float* __restrict__ dc,
                                                   unsigned short* __restrict__ dcwbf) {
  for (int i = threadIdx.x; i < 48 * H_; i += 256) {
    int f = i >> 7, j = i & 127;
    float v;
    if (f < 16)      v = dc[f * H_ + j];
    else if (f < 32) v = dc[f * H_ + j] + dc[(f + 16) * H_ + j];
    else             v = dc[(f + 16) * H_ + j] + dc[(f + 32) * H_ + j];
    dcwbf[i] = f2bf(v);
  }
}

// ---------------- Mi[n][g][64] = (dcw @ W_ih[n]^T)^T via MFMA ----------------
__global__ __launch_bounds__(512) void prep_mi(const float* __restrict__ W_ih,
                                               const unsigned short* __restrict__ dcwbf,
                                               unsigned short* __restrict__ Mi) {
  const int n = blockIdx.x, tid = threadIdx.x;
  const int w = tid >> 6, l = tid & 63, l15 = l & 15, lhi = l >> 4;
  unsigned short* mi_n = Mi + (size_t)n * G3 * 64;
  // zero-fill pad cols 48..63
  for (int i = tid; i < G3 * 16; i += 512)
    mi_n[(i >> 4) * 64 + 48 + (i & 15)] = 0;

  // B-frags: dcw rows f (3 f-tiles), contiguous k
  short8 bft[3][4];
  #pragma unroll
  for (int ft = 0; ft < 3; ++ft)
    #pragma unroll
    for (int ks = 0; ks < 4; ++ks)
      bft[ft][ks] = *(const short8*)(dcwbf + (ft * 16 + l15) * H_ + ks * 32 + lhi * 8);

  // A-frags: W_ih rows g (3 g-tiles per wave), fp32 -> bf16
  f32x4 acc[3][3];
  #pragma unroll
  for (int gt = 0; gt < 3; ++gt)
    #pragma unroll
    for (int ft = 0; ft < 3; ++ft)
      acc[gt][ft] = (f32x4){0.f, 0.f, 0.f, 0.f};

  #pragma unroll
  for (int gt = 0; gt < 3; ++gt) {
    const int g = (w * 3 + gt) * 16 + l15;
    const float* wr = W_ih + ((size_t)n * G3 + g) * H_;
    #pragma unroll
    for (int ks = 0; ks < 4; ++ks) {
      const float4* p = (const float4*)(wr + ks * 32 + lhi * 8);
      float4 a = p[0], b = p[1];
      short8 af;
      af[0]=(short)f2bf(a.x); af[1]=(short)f2bf(a.y); af[2]=(short)f2bf(a.z); af[3]=(short)f2bf(a.w);
      af[4]=(short)f2bf(b.x); af[5]=(short)f2bf(b.y); af[6]=(short)f2bf(b.z); af[7]=(short)f2bf(b.w);
      #pragma unroll
      for (int ft = 0; ft < 3; ++ft)
        acc[gt][ft] = MFMA(af, bft[ft][ks], acc[gt][ft], 0, 0, 0);
    }
  }
  #pragma unroll
  for (int gt = 0; gt < 3; ++gt) {
    const int g0 = (w * 3 + gt) * 16;
    #pragma unroll
    for (int ft = 0; ft < 3; ++ft)
      #pragma unroll
      for (int r = 0; r < 4; ++r)
        mi_n[(size_t)(g0 + lhi * 4 + r) * 64 + ft * 16 + l15] = f2bf(acc[gt][ft][r]);
  }
}

// ---------------- S1 = A@X, S2 = A2@X  (z selects hop), K=512 ----------------
__global__ __launch_bounds__(512) void gemm_s(const unsigned short* __restrict__ xbf,
                                              const unsigned short* __restrict__ asbf,
                                              unsigned short* __restrict__ S1,
                                              unsigned short* __restrict__ S2) {
  __shared__ unsigned short Al[128 * 72];
  __shared__ unsigned short Xl[256 * 72];
  const int z = blockIdx.z;
  const int m0 = blockIdx.y * 128;
  const int j0 = blockIdx.x * 256;
  const unsigned short* As = asbf + (size_t)z * N_ * N_;
  unsigned short* Sd = z ? S2 : S1;
  const int tid = threadIdx.x;
  const int w = tid >> 6, l = tid & 63, l15 = l & 15, lhi = l >> 4;
  const int wm = w >> 2, wj = w & 3;

  f32x4 acc[4][4];
  #pragma unroll
  for (int mt = 0; mt < 4; ++mt)
    #pragma unroll
    for (int jt = 0; jt < 4; ++jt)
      acc[mt][jt] = (f32x4){0.f, 0.f, 0.f, 0.f};

  for (int kt = 0; kt < 8; ++kt) {
    const int k0 = kt * 64;
    // stage A-tile [128 rows n][64 k=m], pad 72
    #pragma unroll
    for (int it = 0; it < 2; ++it) {
      int idx = it * 512 + tid;
      int row = idx >> 3, mc = (idx & 7) * 8;
      short8 v = *(const short8*)(As + (size_t)(m0 + row) * N_ + k0 + mc);
      *(short8*)&Al[row * 72 + mc] = v;
    }
    // stage X-tile transposed: Xl[j 256][k 64], pad 72
    #pragma unroll
    for (int it = 0; it < 4; ++it) {
      int idx = it * 512 + tid;
      int k = idx & 63, jc = idx >> 6;           // jc 0..31
      int j = j0 + jc * 8;
      int b = j / 384, wf = j - b * 384;
      short8 v = *(const short8*)(xbf + ((size_t)(b * N_ + k0 + k)) * 384 + wf);
      #pragma unroll
      for (int i = 0; i < 8; ++i)
        Xl[(jc * 8 + i) * 72 + k] = (unsigned short)v[i];
    }
    __syncthreads();
    #pragma unroll
    for (int ks = 0; ks < 2; ++ks) {
      short8 af[4], bf[4];
      #pragma unroll
      for (int mt = 0; mt < 4; ++mt)
        af[mt] = *(const short8*)&Al[(wm * 64 + mt * 16 + l15) * 72 + ks * 32 + lhi * 8];
      #pragma unroll
      for (int jt = 0; jt < 4; ++jt)
        bf[jt] = *(const short8*)&Xl[(wj * 64 + jt * 16 + l15) * 72 + ks * 32 + lhi * 8];
      #pragma unroll
      for (int mt = 0; mt < 4; ++mt)
        #pragma unroll
        for (int jt = 0; jt < 4; ++jt)
          acc[mt][jt] = MFMA(af[mt], bf[jt], acc[mt][jt], 0, 0, 0);
    }
    __syncthreads();
  }
  #pragma unroll
  for (int mt = 0; mt < 4; ++mt)
    #pragma unroll
    for (int jt = 0; jt < 4; ++jt)
      #pragma unroll
      for (int r = 0; r < 4; ++r) {
        int row = m0 + wm * 64 + mt * 16 + lhi * 4 + r;
        int col = j0 + wj * 64 + jt * 16 + l15;
        Sd[(size_t)row * XCOLS + col] = f2bf(acc[mt][jt][r]);
      }
}

// ---------------- fused GRU v3.1: frag-packed LDS, NO vgpr cap ----------------
// s frag: s_lds[buf][mt][ks2][lane][8]; h frag: h_lds[buf][mt][ks4][lane][8]
__global__ __launch_bounds__(512) void gru_mfma(
    const unsigned short* __restrict__ xbf, const unsigned short* __restrict__ S1,
    const unsigned short* __restrict__ S2, const unsigned short* __restrict__ Mi,
    const float* __restrict__ W_hh, const float* __restrict__ b_ih,
    const float* __restrict__ b_hh, const float* __restrict__ W_out,
    const float* __restrict__ b_out, float* __restrict__ out) {
  __shared__ __align__(16) unsigned short s_lds[2 * 4096];   // 2 buf * 4 mt * 2 ks * 512
  __shared__ __align__(16) unsigned short h_lds[2 * 8192];   // 2 buf * 4 mt * 4 ks * 512
  __shared__ float wout_lds[H_ * F_];

  const int n = blockIdx.x;
  const int tid = threadIdx.x;
  const int w = tid >> 6;        // wave = hidden tile
  const int l = tid & 63;
  const int l15 = l & 15;
  const int lhi = l >> 4;

  { // zero h buf0
    uint* hz = (uint*)h_lds;
    for (int i = tid; i < 4096; i += 512) hz[i] = 0u;
  }
  for (int i = tid; i < H_ * F_; i += 512) wout_lds[i] = W_out[i];

  // weight fragments (register-resident, all 24 steps)
  short8 whf[3][4];
  short8 mif[3][2];
  const float* whh_n = W_hh + (size_t)n * G3 * H_;
  const unsigned short* mi_n = Mi + (size_t)n * G3 * 64;
  #pragma unroll
  for (int g3 = 0; g3 < 3; ++g3) {
    const int grow = g3 * H_ + w * 16 + l15;
    #pragma unroll
    for (int ks = 0; ks < 4; ++ks) {
      const float4* p = (const float4*)(whh_n + (size_t)grow * H_ + ks * 32 + lhi * 8);
      float4 a = p[0], b2 = p[1];
      short8 r;
      r[0]=(short)f2bf(a.x); r[1]=(short)f2bf(a.y); r[2]=(short)f2bf(a.z); r[3]=(short)f2bf(a.w);
      r[4]=(short)f2bf(b2.x); r[5]=(short)f2bf(b2.y); r[6]=(short)f2bf(b2.z); r[7]=(short)f2bf(b2.w);
      whf[g3][ks] = r;
    }
    #pragma unroll
    for (int ks = 0; ks < 2; ++ks)
      mif[g3][ks] = *(const short8*)(mi_n + (size_t)grow * 64 + ks * 32 + lhi * 8);
  }
  // biases in C registers
  f32x4 cR, cZ, cN, cHN, zero4 = {0.f, 0.f, 0.f, 0.f};
  {
    const float* bi = b_ih + n * G3;
    const float* bh = b_hh + n * G3;
    #pragma unroll
    for (int r = 0; r < 4; ++r) {
      int g0 = w * 16 + lhi * 4 + r;
      cR[r]  = bi[g0] + bh[g0];
      cZ[r]  = bi[H_ + g0] + bh[H_ + g0];
      cN[r]  = bi[2 * H_ + g0];
      cHN[r] = bh[2 * H_ + g0];
    }
  }

  // staging geometry (one 16B chunk per thread per step)
  const int smt = tid >> 7, sks = (tid >> 6) & 1, slane = tid & 63;
  const int sc = slane & 15, sfb = sks * 4 + (slane >> 4);
  const int sb = smt * 16 + sc;
  const bool szero = (sfb >= 6);
  const unsigned short* ssrc;
  if (sfb < 2)      ssrc = xbf + ((size_t)(sb * N_ + n)) * 384 + (sfb & 1) * 8;
  else if (sfb < 4) ssrc = S1 + (size_t)n * XCOLS + sb * 384 + (sfb & 1) * 8;
  else              ssrc = S2 + (size_t)n * XCOLS + sb * 384 + (sfb & 1) * 8;

  // prologue: s(t=0) into buf0; zero-chunks into BOTH buffers
  {
    short8 sv = {0,0,0,0,0,0,0,0};
    if (!szero) sv = *(const short8*)ssrc;
    *(short8*)&s_lds[tid * 8] = sv;
    if (szero) *(short8*)&s_lds[4096 + tid * 8] = sv;
  }
  __syncthreads();

  // combine write geometry
  const int hks = w >> 1;
  const int lanep = ((w & 1) * 2 + (lhi >> 1)) * 16 + l15;
  const int j0p = (lhi & 1) * 4;

  int cur = 0;
  for (int t = 0; t < W_; ++t) {
    const int nxt = cur ^ 1;
    const bool dn = (t + 1 < W_);
    short8 svn;
    if (dn && !szero) svn = *(const short8*)(ssrc + (size_t)(t + 1) * 16);

    #pragma unroll
    for (int mt = 0; mt < 4; ++mt) {
      const unsigned short* sb_ = &s_lds[cur * 4096 + mt * 1024 + l * 8];
      const unsigned short* hb_ = &h_lds[cur * 8192 + mt * 2048 + l * 8];
      short8 bs0 = *(const short8*)sb_;
      short8 bs1 = *(const short8*)(sb_ + 512);
      short8 bh0 = *(const short8*)hb_;
      short8 bh1 = *(const short8*)(hb_ + 512);
      short8 bh2 = *(const short8*)(hb_ + 1024);
      short8 bh3 = *(const short8*)(hb_ + 1536);

      f32x4 aR = MFMA(mif[0][0], bs0, cR, 0, 0, 0);
      f32x4 aZ = MFMA(mif[1][0], bs0, cZ, 0, 0, 0);
      f32x4 aN = MFMA(mif[2][0], bs0, cN, 0, 0, 0);
      aR = MFMA(mif[0][1], bs1, aR, 0, 0, 0);
      aZ = MFMA(mif[1][1], bs1, aZ, 0, 0, 0);
      aN = MFMA(mif[2][1], bs1, aN, 0, 0, 0);
      f32x4 hR = MFMA(whf[0][0], bh0, zero4, 0, 0, 0);
      f32x4 hZ = MFMA(whf[1][0], bh0, zero4, 0, 0, 0);
      f32x4 hN = MFMA(whf[2][0], bh0, cHN, 0, 0, 0);
      hR = MFMA(whf[0][1], bh1, hR, 0, 0, 0);
      hZ = MFMA(whf[1][1], bh1, hZ, 0, 0, 0);
      hN = MFMA(whf[2][1], bh1, hN, 0, 0, 0);
      hR = MFMA(whf[0][2], bh2, hR, 0, 0, 0);
      hZ = MFMA(whf[1][2], bh2, hZ, 0, 0, 0);
      hN = MFMA(whf[2][2], bh2, hN, 0, 0, 0);
      hR = MFMA(whf[0][3], bh3, hR, 0, 0, 0);
      hZ = MFMA(whf[1][3], bh3, hZ, 0, 0, 0);
      hN = MFMA(whf[2][3], bh3, hN, 0, 0, 0);

      const int hidx = cur * 8192 + mt * 2048 + hks * 512 + lanep * 8 + j0p;
      const int nidx = nxt * 8192 + mt * 2048 + hks * 512 + lanep * 8 + j0p;
      ushort4 hp4 = *(const ushort4*)&h_lds[hidx];
      ushort4 hn4;
      #pragma unroll
      for (int r = 0; r < 4; ++r) {
        float rg = __builtin_amdgcn_rcpf(1.f + __expf(-(aR[r] + hR[r])));
        float zg = __builtin_amdgcn_rcpf(1.f + __expf(-(aZ[r] + hZ[r])));
        float tt = aN[r] + rg * hN[r];
        float e  = __expf(2.f * tt);
        float th = 1.f - 2.f * __builtin_amdgcn_rcpf(e + 1.f);
        float hp = bf2f(r == 0 ? hp4.x : r == 1 ? hp4.y : r == 2 ? hp4.z : hp4.w);
        float hv = th + zg * (hp - th);
        unsigned short hb = f2bf(hv);
        if (r == 0) hn4.x = hb; else if (r == 1) hn4.y = hb;
        else if (r == 2) hn4.z = hb; else hn4.w = hb;
      }
      *(ushort4*)&h_lds[nidx] = hn4;
    }

    if (dn && !szero) *(short8*)&s_lds[nxt * 4096 + tid * 8] = svn;
    __syncthreads();
    cur = nxt;
  }

  // epilogue: out[b][n][f] = h . W_out[:,f] + b_out[f]
  for (int e = tid; e < B_ * F_; e += 512) {
    const int b = e >> 4, f = e & 15;
    const int mt = b >> 4, c = b & 15;
    float acc = b_out[f];
    #pragma unroll
    for (int ks = 0; ks < 4; ++ks)
      #pragma unroll
      for (int lh = 0; lh < 4; ++lh) {
        const unsigned short* hb = &h_lds[cur * 8192 + mt * 2048 + ks * 512 + (lh * 16 + c) * 8];
        #pragma unroll
        for (int jj = 0; jj < 8; ++jj)
          acc += bf2f(hb[jj]) * wout_lds[(ks * 32 + lh * 8 + jj) * F_ + f];
      }
    out[((size_t)b * N_ + n) * F_ + f] = acc;
  }
}

extern "C" void kernel_launch(void* const* d_in, const int* in_sizes, int n_in,
                              void* d_out, int out_size, void* d_ws, size_t ws_size,
                              hipStream_t stream) {
  const float* x     = (const float*)d_in[0];
  const float* A_fw  = (const float*)d_in[1];
  const float* dc    = (const float*)d_in[2];
  const float* W_ih  = (const float*)d_in[3];
  const float* W_hh  = (const float*)d_in[4];
  const float* b_ih  = (const float*)d_in[5];
  const float* b_hh  = (const float*)d_in[6];
  const float* W_out = (const float*)d_in[7];
  const float* b_out = (const float*)d_in[8];
  float* out = (float*)d_out;

  // workspace (~102 MB)
  unsigned short* xbf   = (unsigned short*)d_ws;            // 12.58M
  unsigned short* S1    = xbf + (size_t)B_ * N_ * W_ * F_;  // 12.58M
  unsigned short* S2    = S1 + (size_t)N_ * XCOLS;          // 12.58M
  unsigned short* Mi    = S2 + (size_t)N_ * XCOLS;          // 12.58M
  unsigned short* asbf  = Mi + (size_t)N_ * G3 * 64;        // 2*512*512
  unsigned short* dcwbf = asbf + 2 * N_ * N_;               // 48*128

  cvt_bf16<<<dim3(6144), dim3(256), 0, stream>>>(x, xbf);
  ab_build<<<dim3(128), dim3(256), 0, stream>>>(A_fw, asbf);
  dcwbf_build<<<dim3(1), dim3(256), 0, stream>>>(dc, dcwbf);
  prep_mi<<<dim3(N_), dim3(512), 0, stream>>>(W_ih, dcwbf, Mi);
  gemm_s<<<dim3(96, 4, 2), dim3(512), 0, stream>>>(xbf, asbf, S1, S2);
  gru_mfma<<<dim3(N_), dim3(512), 0, stream>>>(xbf, S1, S2, Mi, W_hh, b_ih, b_hh,
                                               W_out, b_out, out);
}